// Round 2
// baseline (378.951 us; speedup 1.0000x reference)
//
#include <hip/hip_runtime.h>
#include <math.h>

#define NG   2048
#define NN   48
#define FIN  64
#define HIDC 128
#define DEG  8
#define EPG  (NN*DEG)   // 384 edges per graph
#define NATT 8
#define KTOP 4
#define NTH  256
#define OUTW (KTOP*HIDC + NATT)  // 520

struct SM {
  float hA[NN*HIDC];        // 6144
  float hB[NN*HIDC];        // 6144
  float alpha[EPG];         // per-edge alpha; reused as logits/att (48*8=384)
  float ssrc[NN], sdst[NN], aself[NN];
  float rs[NN], sc[NN];
  float red[16];
  float misc[4];
  float valk[KTOP];
  int   idxk[KTOP];
  int   csr_src[EPG];
  int   row_start[NN+1];
  int   fill[NN];
};

template<int KD>
__device__ __forceinline__ void gemm48(const float* in, const float* __restrict__ W,
                                       int t, float acc[6][4]) {
  const int col = t & 31, row = t >> 5;
  const int c0 = col * 4, n0 = row * 6;
  #pragma unroll
  for (int i = 0; i < 6; ++i)
    #pragma unroll
    for (int j = 0; j < 4; ++j) acc[i][j] = 0.f;
  for (int kb = 0; kb < KD; kb += 4) {
    float4 w0 = *(const float4*)(W + (size_t)(kb+0)*HIDC + c0);
    float4 w1 = *(const float4*)(W + (size_t)(kb+1)*HIDC + c0);
    float4 w2 = *(const float4*)(W + (size_t)(kb+2)*HIDC + c0);
    float4 w3 = *(const float4*)(W + (size_t)(kb+3)*HIDC + c0);
    #pragma unroll
    for (int i = 0; i < 6; ++i) {
      float4 h = *(const float4*)(in + (n0+i)*KD + kb);
      acc[i][0] = fmaf(h.w, w3.x, fmaf(h.z, w2.x, fmaf(h.y, w1.x, fmaf(h.x, w0.x, acc[i][0]))));
      acc[i][1] = fmaf(h.w, w3.y, fmaf(h.z, w2.y, fmaf(h.y, w1.y, fmaf(h.x, w0.y, acc[i][1]))));
      acc[i][2] = fmaf(h.w, w3.z, fmaf(h.z, w2.z, fmaf(h.y, w1.z, fmaf(h.x, w0.z, acc[i][2]))));
      acc[i][3] = fmaf(h.w, w3.w, fmaf(h.z, w2.w, fmaf(h.y, w1.w, fmaf(h.x, w0.w, acc[i][3]))));
    }
  }
}

template<int KD, bool RELU>
__device__ __forceinline__ void gat_layer(SM& s, const float* in, float* hmid, float* outbuf,
                                          const float* __restrict__ W,
                                          const float* __restrict__ avs,
                                          const float* __restrict__ avd,
                                          const float* __restrict__ bias,
                                          const float* __restrict__ lnw,
                                          const float* __restrict__ lnb, int t) {
  float acc[6][4];
  gemm48<KD>(in, W, t, acc);
  const int col = t & 31, row = t >> 5, c0 = col * 4, n0 = row * 6;
  // store h (no bias) + attention-scalar epilogue
  float4 asv = *(const float4*)(avs + c0);
  float4 adv = *(const float4*)(avd + c0);
  #pragma unroll
  for (int i = 0; i < 6; ++i) {
    float4 v = make_float4(acc[i][0], acc[i][1], acc[i][2], acc[i][3]);
    *(float4*)(hmid + (n0+i)*HIDC + c0) = v;
    float ps = v.x*asv.x + v.y*asv.y + v.z*asv.z + v.w*asv.w;
    float pd = v.x*adv.x + v.y*adv.y + v.z*adv.z + v.w*adv.w;
    #pragma unroll
    for (int off = 16; off > 0; off >>= 1) {
      ps += __shfl_xor(ps, off, 32);
      pd += __shfl_xor(pd, off, 32);
    }
    if (col == 0) { s.ssrc[n0+i] = ps; s.sdst[n0+i] = pd; }
  }
  __syncthreads();
  // per-node softmax alpha over incoming edges (+self loop)
  if (t < NN) {
    const int i = t;
    float si = s.ssrc[i], di = s.sdst[i];
    float es = si + di; es = es > 0.f ? es : 0.2f*es;
    float m = es;
    const int b0 = s.row_start[i], b1 = s.row_start[i+1];
    for (int q = b0; q < b1; ++q) {
      float e = s.ssrc[s.csr_src[q]] + di; e = e > 0.f ? e : 0.2f*e;
      s.alpha[q] = e; m = fmaxf(m, e);
    }
    float pself = expf(es - m);
    float z = pself;
    for (int q = b0; q < b1; ++q) { float p = expf(s.alpha[q] - m); s.alpha[q] = p; z += p; }
    float inv = 1.f / (z + 1e-16f);
    s.aself[i] = pself * inv;
    for (int q = b0; q < b1; ++q) s.alpha[q] *= inv;
  }
  __syncthreads();
  // aggregate messages + bias
  {
    const int c = t & (HIDC-1), grp = t >> 7;
    const float bc = bias[c];
    for (int i = grp; i < NN; i += 2) {
      float a = s.aself[i];
      float av = a * hmid[i*HIDC + c];
      const int b0 = s.row_start[i], b1 = s.row_start[i+1];
      for (int q = b0; q < b1; ++q) av += s.alpha[q] * hmid[s.csr_src[q]*HIDC + c];
      outbuf[i*HIDC + c] = av + bc;
    }
  }
  __syncthreads();
  // graph-LN (+ optional relu), over all 48*128 values
  float lsum = 0.f, lsq = 0.f;
  for (int e = t; e < NN*HIDC; e += NTH) { float v = outbuf[e]; lsum += v; lsq += v*v; }
  #pragma unroll
  for (int off = 32; off > 0; off >>= 1) { lsum += __shfl_xor(lsum, off, 64); lsq += __shfl_xor(lsq, off, 64); }
  const int wid = t >> 6;
  if ((t & 63) == 0) { s.red[wid] = lsum; s.red[8+wid] = lsq; }
  __syncthreads();
  if (t == 0) {
    float su = 0.f, sq = 0.f;
    for (int i = 0; i < 4; ++i) { su += s.red[i]; sq += s.red[8+i]; }
    const float inv_n = 1.f / (NN*HIDC);
    float mu = su * inv_n;
    float var = sq * inv_n - mu*mu;
    s.misc[0] = mu; s.misc[1] = 1.f / sqrtf(var + 1e-5f);
  }
  __syncthreads();
  {
    const float mu = s.misc[0], rstd = s.misc[1];
    const int c = t & (HIDC-1);
    const float wc = lnw[c], bcn = lnb[c];
    for (int e = t; e < NN*HIDC; e += NTH) {
      float v = (outbuf[e] - mu) * rstd * wc + bcn;
      if (RELU) v = fmaxf(v, 0.f);
      outbuf[e] = v;
    }
  }
  __syncthreads();
}

__global__ __launch_bounds__(NTH)
void gat_fused(const float* __restrict__ x,
               const int* __restrict__ edge_src, const int* __restrict__ edge_dst,
               const float* __restrict__ W1, const float* __restrict__ as1, const float* __restrict__ ad1, const float* __restrict__ b1,
               const float* __restrict__ W2, const float* __restrict__ as2, const float* __restrict__ ad2, const float* __restrict__ b2,
               const float* __restrict__ W3, const float* __restrict__ as3, const float* __restrict__ ad3, const float* __restrict__ b3,
               const float* __restrict__ ln1w, const float* __restrict__ ln1b,
               const float* __restrict__ ln2w, const float* __restrict__ ln2b,
               const float* __restrict__ ln3w, const float* __restrict__ ln3b,
               const float* __restrict__ poolw,
               const float* __restrict__ fc1w, const float* __restrict__ fc1b,
               const float* __restrict__ fc2w, const float* __restrict__ fc2b,
               float* __restrict__ out) {
  __shared__ SM s;
  const int g = blockIdx.x, t = threadIdx.x;
  const int base = g * NN;

  // stage x [48][64] into hA
  for (int e = t; e < NN*FIN; e += NTH) s.hA[e] = x[(size_t)base*FIN + e];

  // build per-graph CSR (incoming lists) in LDS
  if (t < NN) s.fill[t] = 0;
  __syncthreads();
  for (int e = t; e < EPG; e += NTH) atomicAdd(&s.fill[edge_dst[(size_t)g*EPG + e] - base], 1);
  __syncthreads();
  if (t == 0) {
    int acc0 = 0;
    for (int i = 0; i < NN; ++i) { s.row_start[i] = acc0; acc0 += s.fill[i]; }
    s.row_start[NN] = acc0;
  }
  __syncthreads();
  if (t < NN) s.fill[t] = s.row_start[t];
  __syncthreads();
  for (int e = t; e < EPG; e += NTH) {
    int d  = edge_dst[(size_t)g*EPG + e] - base;
    int sl = edge_src[(size_t)g*EPG + e] - base;
    int pos = atomicAdd(&s.fill[d], 1);
    s.csr_src[pos] = sl;
  }
  __syncthreads();

  gat_layer<FIN,  true >(s, s.hA, s.hB, s.hA, W1, as1, ad1, b1, ln1w, ln1b, t);
  gat_layer<HIDC, true >(s, s.hA, s.hB, s.hA, W2, as2, ad2, b2, ln2w, ln2b, t);
  gat_layer<HIDC, false>(s, s.hA, s.hB, s.hA, W3, as3, ad3, b3, ln3w, ln3b, t);

  // 1/||pool_w||
  if (t < 64) {
    float v = poolw[t]*poolw[t] + poolw[t+64]*poolw[t+64];
    #pragma unroll
    for (int off = 32; off > 0; off >>= 1) v += __shfl_xor(v, off, 64);
    if (t == 0) s.misc[2] = 1.f / sqrtf(v);
  }
  __syncthreads();

  // scores (tanh(h.pool_w/||w||)) and row sums of h
  {
    const int col = t & 31, row = t >> 5, n0 = row * 6;
    float pwv[4];
    #pragma unroll
    for (int q = 0; q < 4; ++q) pwv[q] = poolw[col + 32*q];
    const float invn = s.misc[2];
    #pragma unroll
    for (int i = 0; i < 6; ++i) {
      float d = 0.f, r = 0.f;
      #pragma unroll
      for (int q = 0; q < 4; ++q) { float v = s.hA[(n0+i)*HIDC + col + 32*q]; d += v*pwv[q]; r += v; }
      #pragma unroll
      for (int off = 16; off > 0; off >>= 1) { d += __shfl_xor(d, off, 32); r += __shfl_xor(r, off, 32); }
      if (col == 0) { s.sc[n0+i] = tanhf(d * invn); s.rs[n0+i] = r; }
    }
  }
  __syncthreads();

  // top-4 (strict >, earliest index wins — matches lax.top_k stability)
  if (t == 0) {
    unsigned long long used = 0ull;
    for (int k = 0; k < KTOP; ++k) {
      float best = -1e30f; int bi = 0;
      for (int n = 0; n < NN; ++n)
        if (!((used >> n) & 1ull) && s.sc[n] > best) { best = s.sc[n]; bi = n; }
      used |= 1ull << bi;
      s.idxk[k] = bi; s.valk[k] = best;
    }
  }
  __syncthreads();

  float* og = out + (size_t)g * OUTW;
  for (int o = t; o < KTOP*HIDC; o += NTH) {
    int k = o >> 7, c = o & 127;
    og[o] = s.hA[s.idxk[k]*HIDC + c] * s.valk[k];
  }

  // t = tanh(h @ fc1 + fc1_b) -> hB
  {
    float acc[6][4];
    gemm48<HIDC>(s.hA, fc1w, t, acc);
    const int col = t & 31, row = t >> 5, c0 = col*4, n0 = row*6;
    float4 bv = *(const float4*)(fc1b + c0);
    #pragma unroll
    for (int i = 0; i < 6; ++i) {
      float4 v;
      v.x = tanhf(acc[i][0] + bv.x); v.y = tanhf(acc[i][1] + bv.y);
      v.z = tanhf(acc[i][2] + bv.z); v.w = tanhf(acc[i][3] + bv.w);
      *(float4*)(s.hB + (n0+i)*HIDC + c0) = v;
    }
  }
  __syncthreads();

  // logits[n][a] = t[n] @ fc2 + fc2_b  -> s.alpha (reused, 48*8)
  {
    const int col = t & 31, row = t >> 5, n0 = row * 6;
    #pragma unroll
    for (int i = 0; i < 6; ++i) {
      float lg[NATT];
      #pragma unroll
      for (int a = 0; a < NATT; ++a) lg[a] = 0.f;
      #pragma unroll
      for (int q = 0; q < 4; ++q) {
        float v = s.hB[(n0+i)*HIDC + col + 32*q];
        const float* f2 = fc2w + (size_t)(col + 32*q)*NATT;
        #pragma unroll
        for (int a = 0; a < NATT; ++a) lg[a] += v * f2[a];
      }
      #pragma unroll
      for (int a = 0; a < NATT; ++a) {
        #pragma unroll
        for (int off = 16; off > 0; off >>= 1) lg[a] += __shfl_xor(lg[a], off, 32);
      }
      if (col == 0) {
        #pragma unroll
        for (int a = 0; a < NATT; ++a) s.alpha[(n0+i)*NATT + a] = lg[a] + fc2b[a];
      }
    }
  }
  __syncthreads();

  // softmax over nodes per attention head; avg[a] = (1/8) sum_n att[n,a]*rowsum(h[n])
  if (t < NATT) {
    const int a = t;
    float m = -1e30f;
    for (int n = 0; n < NN; ++n) m = fmaxf(m, s.alpha[n*NATT + a]);
    float z = 0.f;
    for (int n = 0; n < NN; ++n) z += expf(s.alpha[n*NATT + a] - m);
    const float zi = 1.f / z;
    float acc0 = 0.f;
    for (int n = 0; n < NN; ++n) acc0 += expf(s.alpha[n*NATT + a] - m) * zi * s.rs[n];
    og[KTOP*HIDC + a] = acc0 * (1.0f / NATT);
  }
}

extern "C" void kernel_launch(void* const* d_in, const int* in_sizes, int n_in,
                              void* d_out, int out_size, void* d_ws, size_t ws_size,
                              hipStream_t stream) {
  (void)in_sizes; (void)n_in; (void)d_ws; (void)ws_size; (void)out_size;
  const float* x    = (const float*)d_in[0];
  const int*   esrc = (const int*)  d_in[1];
  const int*   edst = (const int*)  d_in[2];
  // d_in[3] = batch (implicit in layout, unused)
  const float* W1   = (const float*)d_in[4];
  const float* as1  = (const float*)d_in[5];
  const float* ad1  = (const float*)d_in[6];
  const float* b1   = (const float*)d_in[7];
  const float* W2   = (const float*)d_in[8];
  const float* as2  = (const float*)d_in[9];
  const float* ad2  = (const float*)d_in[10];
  const float* b2   = (const float*)d_in[11];
  const float* W3   = (const float*)d_in[12];
  const float* as3  = (const float*)d_in[13];
  const float* ad3  = (const float*)d_in[14];
  const float* b3   = (const float*)d_in[15];
  const float* ln1w = (const float*)d_in[16];
  const float* ln1b = (const float*)d_in[17];
  const float* ln2w = (const float*)d_in[18];
  const float* ln2b = (const float*)d_in[19];
  const float* ln3w = (const float*)d_in[20];
  const float* ln3b = (const float*)d_in[21];
  const float* pw   = (const float*)d_in[22];
  const float* fc1w = (const float*)d_in[23];
  const float* fc1b = (const float*)d_in[24];
  const float* fc2w = (const float*)d_in[25];
  const float* fc2b = (const float*)d_in[26];
  float* out = (float*)d_out;

  gat_fused<<<NG, NTH, 0, stream>>>(x, esrc, edst,
                                    W1, as1, ad1, b1,
                                    W2, as2, ad2, b2,
                                    W3, as3, ad3, b3,
                                    ln1w, ln1b, ln2w, ln2b, ln3w, ln3b,
                                    pw, fc1w, fc1b, fc2w, fc2b, out);
}